// Round 1
// baseline (12496.466 us; speedup 1.0000x reference)
//
#include <hip/hip_runtime.h>
#include <hip/hip_bf16.h>

#define NB 128   // batch
#define NT 512   // time steps
#define NI 256   // input dim (== NH for both layers)
#define NH 256   // hidden dim
#define GH 8     // H-split workgroups per batch group
#define GB 32    // batch groups
#define BC 4     // batch rows per group (NB/GB)
#define JC 32    // h-columns owned per wg (NH/GH)
#define NROWS 96 // weight rows per wg = 3*JC
#define WPAD 264 // padded bf16 row stride (264*2B = 528B -> conflict-free-ish)
#define NTH 384  // 3 gates * 32 j * 4 b

typedef unsigned int u32;
typedef unsigned short u16;

__device__ __forceinline__ float lo_bf(u32 u) { return __uint_as_float(u << 16); }
__device__ __forceinline__ float hi_bf(u32 u) { return __uint_as_float(u & 0xffff0000u); }
__device__ __forceinline__ u16 f2bf(float f) {
  u32 u = __float_as_uint(f);
  u += 0x7fffu + ((u >> 16) & 1u);   // round-to-nearest-even
  return (u16)(u >> 16);
}
__device__ __forceinline__ float sigmoidf_(float v) { return 1.0f / (1.0f + __expf(-v)); }

// One GRU layer. Grid = GB*GH workgroups (all co-resident: 1 wg/CU).
// blockIdx.x = gh*GB + gb  (group members at id stride GB -> same XCD under round-robin)
__global__ __launch_bounds__(NTH) void gru_layer_kernel(
    const float* __restrict__ in_f32,   // layer0 input (fp32) or nullptr
    const u16*   __restrict__ in_bf16,  // layer1 input (bf16) or nullptr
    const float* __restrict__ Wih,      // [3*NH, NI]
    const float* __restrict__ Whh,      // [3*NH, NH]
    const float* __restrict__ bih,      // [3*NH]
    const float* __restrict__ bhh,      // [3*NH]
    u16*         __restrict__ out_seq,  // bf16 [NB,NT,NH] or nullptr
    float*       __restrict__ hbuf,     // fp32 [2,NB,NH] exchange buffer
    u32*         __restrict__ cnt)      // [GB*32] per-group counters (zeroed per launch)
{
  const int gb  = blockIdx.x & (GB - 1);
  const int gh  = blockIdx.x >> 5;
  const int tid = threadIdx.x;
  const int j0  = gh * JC;
  const int b0  = gb * BC;

  __shared__ u16   Wi[NROWS * WPAD];   // 50688 B
  __shared__ u16   Wh[NROWS * WPAD];   // 50688 B
  __shared__ float xb[BC][NI];         // 4 KB
  __shared__ float hb[BC][NH];         // 4 KB
  __shared__ float rS[BC][JC];
  __shared__ float zS[BC][JC];
  __shared__ float nxS[BC][JC];
  __shared__ float nhS[BC][JC];

  // ---- load resident weight slices (fp32 -> bf16 in LDS), once per kernel ----
  for (int idx = tid; idx < NROWS * NI; idx += NTH) {
    int rr = idx >> 8;            // local row 0..95 = g*JC + jj
    int k  = idx & (NI - 1);
    int g  = rr >> 5;
    int jj = rr & (JC - 1);
    int grow = g * NH + j0 + jj;  // global weight row
    Wi[rr * WPAD + k] = f2bf(Wih[grow * NI + k]);
    Wh[rr * WPAD + k] = f2bf(Whh[grow * NH + k]);
  }
  for (int idx = tid; idx < BC * NH; idx += NTH) ((float*)hb)[idx] = 0.0f;

  const int g  = tid >> 7;          // gate 0=r 1=z 2=n
  const int jj = (tid & 127) >> 2;  // 0..31
  const int b  = tid & 3;           // 0..3
  const float bi = bih[g * NH + j0 + jj];
  const float bh = bhh[g * NH + j0 + jj];
  const u32* wiRow = (const u32*)&Wi[(g * JC + jj) * WPAD];
  const u32* whRow = (const u32*)&Wh[(g * JC + jj) * WPAD];
  u32* mycnt = cnt + gb * 32;       // 128B-padded per group
  __syncthreads();

  for (int t = 0; t < NT; ++t) {
    // ---- stage x_t rows for our 4 batch elements ----
    for (int idx = tid; idx < BC * NI; idx += NTH) {
      int bb = idx >> 8;
      int k  = idx & (NI - 1);
      size_t off = ((size_t)(b0 + bb) * NT + t) * NI + k;
      xb[bb][k] = in_f32 ? in_f32[off] : lo_bf((u32)in_bf16[off]);
    }
    __syncthreads();

    // ---- two length-256 dot products per thread (input proj + hidden proj) ----
    float ax = bi, ah = bh;
    #pragma unroll 8
    for (int k8 = 0; k8 < NI / 8; ++k8) {
      uint4 wi4 = ((const uint4*)wiRow)[k8];
      uint4 wh4 = ((const uint4*)whRow)[k8];
      const float4* xp = (const float4*)&xb[b][k8 * 8];
      float4 x0 = xp[0], x1 = xp[1];
      const float4* hp = (const float4*)&hb[b][k8 * 8];
      float4 h0 = hp[0], h1 = hp[1];
      ax += lo_bf(wi4.x) * x0.x + hi_bf(wi4.x) * x0.y
          + lo_bf(wi4.y) * x0.z + hi_bf(wi4.y) * x0.w
          + lo_bf(wi4.z) * x1.x + hi_bf(wi4.z) * x1.y
          + lo_bf(wi4.w) * x1.z + hi_bf(wi4.w) * x1.w;
      ah += lo_bf(wh4.x) * h0.x + hi_bf(wh4.x) * h0.y
          + lo_bf(wh4.y) * h0.z + hi_bf(wh4.y) * h0.w
          + lo_bf(wh4.z) * h1.x + hi_bf(wh4.z) * h1.y
          + lo_bf(wh4.w) * h1.z + hi_bf(wh4.w) * h1.w;
    }

    if (g == 0)      rS[b][jj] = sigmoidf_(ax + ah);
    else if (g == 1) zS[b][jj] = sigmoidf_(ax + ah);
    else           { nxS[b][jj] = ax; nhS[b][jj] = ah; }  // bhh_n stays inside r*(...)
    __syncthreads();

    // ---- GRU update for our 32 columns x 4 rows ----
    if (tid < BC * JC) {
      int bb = tid & 3;
      int j  = tid >> 2;
      float r = rS[bb][j], z = zS[bb][j];
      float n = tanhf(nxS[bb][j] + r * nhS[bb][j]);
      float hnew = (1.0f - z) * n + z * hb[bb][j0 + j];
      __hip_atomic_store(&hbuf[((size_t)(t & 1) * NB + (b0 + bb)) * NH + j0 + j],
                         hnew, __ATOMIC_RELAXED, __HIP_MEMORY_SCOPE_AGENT);
      if (out_seq)
        out_seq[((size_t)(b0 + bb) * NT + t) * NH + j0 + j] = f2bf(hnew);
    }
    __syncthreads();

    // ---- monotonic-counter group barrier (release/acquire, device scope) ----
    if (tid == 0) {
      __hip_atomic_fetch_add(mycnt, 1u, __ATOMIC_RELEASE, __HIP_MEMORY_SCOPE_AGENT);
      u32 target = (u32)(t + 1) * GH;
      while (__hip_atomic_load(mycnt, __ATOMIC_ACQUIRE, __HIP_MEMORY_SCOPE_AGENT) < target)
        __builtin_amdgcn_s_sleep(2);
    }
    __syncthreads();

    // ---- read back full h_{t+1} ----
    for (int idx = tid; idx < BC * NH; idx += NTH) {
      int bb = idx >> 8;
      int k  = idx & (NH - 1);
      hb[bb][k] = __hip_atomic_load(
          &hbuf[((size_t)(t & 1) * NB + (b0 + bb)) * NH + k],
          __ATOMIC_RELAXED, __HIP_MEMORY_SCOPE_AGENT);
    }
    __syncthreads();
  }
}

__global__ __launch_bounds__(256) void fc_kernel(const float* __restrict__ hT,
                                                 const float* __restrict__ Wfc,
                                                 const float* __restrict__ bfc,
                                                 float* __restrict__ out) {
  __shared__ float w[NH];
  int tid = threadIdx.x;
  if (tid < NH) w[tid] = Wfc[tid];
  __syncthreads();
  if (tid < NB) {
    float acc = bfc[0];
    for (int j = 0; j < NH; ++j) acc += hT[tid * NH + j] * w[j];
    out[tid] = sigmoidf_(acc);
  }
}

extern "C" void kernel_launch(void* const* d_in, const int* in_sizes, int n_in,
                              void* d_out, int out_size, void* d_ws, size_t ws_size,
                              hipStream_t stream) {
  const float* x    = (const float*)d_in[0];
  const float* Wih0 = (const float*)d_in[1];
  const float* Whh0 = (const float*)d_in[2];
  const float* bih0 = (const float*)d_in[3];
  const float* bhh0 = (const float*)d_in[4];
  const float* Wih1 = (const float*)d_in[5];
  const float* Whh1 = (const float*)d_in[6];
  const float* bih1 = (const float*)d_in[7];
  const float* bhh1 = (const float*)d_in[8];
  const float* Wfc  = (const float*)d_in[9];
  const float* bfc  = (const float*)d_in[10];

  char* ws = (char*)d_ws;
  u16*   out0 = (u16*)ws;                                           // 32 MB bf16 [NB,NT,NH]
  float* hbuf = (float*)(ws + (size_t)32 * 1024 * 1024);            // 256 KB
  u32*   cnt  = (u32*)(ws + (size_t)32 * 1024 * 1024 + 262144);     // 4 KB

  // layer 0
  hipMemsetAsync(cnt, 0, GB * 32 * sizeof(u32), stream);
  gru_layer_kernel<<<dim3(GB * GH), dim3(NTH), 0, stream>>>(
      x, nullptr, Wih0, Whh0, bih0, bhh0, out0, hbuf, cnt);
  // layer 1
  hipMemsetAsync(cnt, 0, GB * 32 * sizeof(u32), stream);
  gru_layer_kernel<<<dim3(GB * GH), dim3(NTH), 0, stream>>>(
      nullptr, out0, Wih1, Whh1, bih1, bhh1, nullptr, hbuf, cnt);
  // final FC + sigmoid; h_T lives in hbuf slot (NT-1)&1 == 1
  fc_kernel<<<dim3(1), dim3(256), 0, stream>>>(hbuf + (size_t)NB * NH, Wfc, bfc,
                                               (float*)d_out);
}

// Round 2
// 2529.873 us; speedup vs baseline: 4.9396x; 4.9396x over previous
//
#include <hip/hip_runtime.h>
#include <hip/hip_bf16.h>
#include <stdint.h>

#define NB 128
#define NT 512
#define NI 256
#define NH 256
#define NG 768          // 3*NH

typedef unsigned int u32;
typedef unsigned short u16;
typedef __attribute__((ext_vector_type(8))) short short8;
typedef __attribute__((ext_vector_type(4))) float f32x4;

__device__ __forceinline__ float lo_bf(u32 u){ return __uint_as_float(u << 16); }
__device__ __forceinline__ float hi_bf(u32 u){ return __uint_as_float(u & 0xffff0000u); }
__device__ __forceinline__ u16 f2bf(float f){
  u32 u = __float_as_uint(f);
  u += 0x7fffu + ((u >> 16) & 1u);   // RNE
  return (u16)(u >> 16);
}
__device__ __forceinline__ u32 pack2(float a, float b){
  return (u32)f2bf(a) | ((u32)f2bf(b) << 16);
}
__device__ __forceinline__ float sigf(float v){
  return __builtin_amdgcn_rcpf(1.f + __expf(-v));
}
__device__ __forceinline__ float tanhf_(float u){
  float e = __expf(2.f*u);
  return 1.f - 2.f*__builtin_amdgcn_rcpf(e + 1.f);
}
__device__ __forceinline__ void gload_lds16(const void* g, void* l){
  __builtin_amdgcn_global_load_lds((const __attribute__((address_space(1))) void*)g,
                                   (__attribute__((address_space(3))) void*)l, 16, 0, 0);
}

// ---------------------------------------------------------------------------
// fp32 -> bf16 conversions + combined bias vectors
// ---------------------------------------------------------------------------
__global__ void convert_kernel(const float* __restrict__ x,
    const float* __restrict__ Wih0, const float* __restrict__ Wih1,
    const float* __restrict__ bih0, const float* __restrict__ bhh0,
    const float* __restrict__ bih1, const float* __restrict__ bhh1,
    u16* __restrict__ xbf, u16* __restrict__ w0bf, u16* __restrict__ w1bf,
    float* __restrict__ bias0, float* __restrict__ bias1)
{
  const int NX4 = NB*NT*NI/4, NW4 = NG*NH/4;
  int gid = blockIdx.x*blockDim.x + threadIdx.x;
  for (int i = gid; i < NX4 + 2*NW4; i += gridDim.x*blockDim.x) {
    const float* s; u16* d; int o;
    if (i < NX4)          { s = x;    d = xbf;  o = i; }
    else if (i < NX4+NW4) { s = Wih0; d = w0bf; o = i - NX4; }
    else                  { s = Wih1; d = w1bf; o = i - NX4 - NW4; }
    float4 v = *(const float4*)(s + (size_t)o*4);
    uint2 pk; pk.x = pack2(v.x, v.y); pk.y = pack2(v.z, v.w);
    *(uint2*)&d[(size_t)o*4] = pk;
  }
  // bias_comb[g] = bih[g] + (g in r,z ? bhh[g] : 0)   (bhh_n stays inside r*(...))
  if (gid < NG)            bias0[gid] = bih0[gid] + (gid < 2*NH ? bhh0[gid] : 0.f);
  else if (gid < 2*NG)   { int g = gid - NG; bias1[g] = bih1[g] + (g < 2*NH ? bhh1[g] : 0.f); }
}

// ---------------------------------------------------------------------------
// xproj[m][g] = sum_k A[m][k] * W[g][k] + bias[g]    (A:[M][256], W:[768][256])
// 64x32 tiles, K=256 single shot, XOR-swizzled LDS via pre-swizzled gload_lds src
// ---------------------------------------------------------------------------
__global__ __launch_bounds__(256, 2) void gemm_proj(const u16* __restrict__ A,
    const u16* __restrict__ W, const float* __restrict__ bias, u16* __restrict__ out)
{
  const int mt = blockIdx.x / 24, nt = blockIdx.x % 24;
  __shared__ __align__(16) u16 As[64*256];   // 32 KB
  __shared__ __align__(16) u16 Bs[32*256];   // 16 KB
  const int tid = threadIdx.x;
  const u16* Ag = A + (size_t)mt*64*256;
  const u16* Wg = W + (size_t)nt*32*256;
  #pragma unroll
  for (int i = 0; i < 8; ++i) {              // A: 2048 16B chunks
    int ca = tid + 256*i, row = ca >> 5, sl = ca & 31;
    gload_lds16(Ag + row*256 + ((sl ^ (row&7))<<3), &As[ca<<3]);
  }
  #pragma unroll
  for (int i = 0; i < 4; ++i) {              // B: 1024 16B chunks
    int cb = tid + 256*i, row = cb >> 5, sl = cb & 31;
    gload_lds16(Wg + row*256 + ((sl ^ (row&7))<<3), &Bs[cb<<3]);
  }
  __syncthreads();
  const int w = tid >> 6, l = tid & 63, c = l & 15, q = l >> 4;
  f32x4 acc0 = {0.f,0.f,0.f,0.f}, acc1 = acc0;
  const int arow = w*16 + c;
  #pragma unroll
  for (int kb = 0; kb < 8; ++kb) {
    int ks = kb*4 + q;
    short8 af  = *(const short8*)&As[arow*256 + ((ks ^ (arow&7))<<3)];
    short8 bf0 = *(const short8*)&Bs[c*256        + ((ks ^ (c&7))<<3)];
    short8 bf1 = *(const short8*)&Bs[(16+c)*256   + ((ks ^ ((16+c)&7))<<3)];
    acc0 = __builtin_amdgcn_mfma_f32_16x16x32_bf16(af, bf0, acc0, 0,0,0);
    acc1 = __builtin_amdgcn_mfma_f32_16x16x32_bf16(af, bf1, acc1, 0,0,0);
  }
  #pragma unroll
  for (int nf = 0; nf < 2; ++nf) {
    int g = nt*32 + nf*16 + c;
    float bs = bias[g];
    f32x4 av = nf ? acc1 : acc0;
    #pragma unroll
    for (int r = 0; r < 4; ++r) {
      int m = mt*64 + w*16 + q*4 + r;
      out[(size_t)m*NG + g] = f2bf(av[r] + bs);
    }
  }
}

// ---------------------------------------------------------------------------
// GRU recurrence, full hidden per wg, Whh resident in VGPRs.
// grid 16 wgs x 512 thr (8 waves). wave w owns j in [32w, 32w+32), all 3 gates.
// ---------------------------------------------------------------------------
__global__ __launch_bounds__(512, 2) void recur_kernel(
    const u16* __restrict__ xproj,   // [NB*NT][768] bf16, biases folded (r,z incl bhh)
    const float* __restrict__ Whh,   // [768][256] fp32
    const float* __restrict__ bhh,   // [768] fp32 (n part used)
    u16* __restrict__ outp,          // write_all: [NB][NT][256] ; else hT [NB][256]
    int write_all)
{
  const int b0 = blockIdx.x * 8;
  const int tid = threadIdx.x;
  const int w = tid >> 6, l = tid & 63, c = l & 15, q = l >> 4;

  __shared__ __align__(16) u16 hfrag[2][8][512];   // [buf][kblk][lane*8+e], 16 KB
  for (int i = tid; i < 4096; i += 512) ((u32*)hfrag)[i] = 0u;

  // ---- resident weight fragments: wf[gate][jh][kb], 48 frags = 192 VGPR ----
  short8 wf[3][2][8];
  #pragma unroll
  for (int g = 0; g < 3; ++g)
    #pragma unroll
    for (int jh = 0; jh < 2; ++jh) {
      const float* src = Whh + ((size_t)(g*NH + 32*w + jh*16 + c))*NI + q*8;
      #pragma unroll
      for (int kb = 0; kb < 8; ++kb) {
        float4 f0 = *(const float4*)(src + kb*32);
        float4 f1 = *(const float4*)(src + kb*32 + 4);
        short8 s;
        s[0]=(short)f2bf(f0.x); s[1]=(short)f2bf(f0.y);
        s[2]=(short)f2bf(f0.z); s[3]=(short)f2bf(f0.w);
        s[4]=(short)f2bf(f1.x); s[5]=(short)f2bf(f1.y);
        s[6]=(short)f2bf(f1.z); s[7]=(short)f2bf(f1.w);
        wf[g][jh][kb] = s;
      }
    }

  const int jb0 = 32*w + q*4;
  float bhn[2][4];
  #pragma unroll
  for (int jh = 0; jh < 2; ++jh)
    #pragma unroll
    for (int r = 0; r < 4; ++r)
      bhn[jh][r] = bhh[2*NH + jb0 + jh*16 + r];

  const int bb = b0 + (c & 7);                     // c>=8 lanes duplicate (results unused)
  uint2 xp[3][2];
  #pragma unroll
  for (int g = 0; g < 3; ++g)
    #pragma unroll
    for (int jh = 0; jh < 2; ++jh)
      xp[g][jh] = *(const uint2*)&xproj[(size_t)bb*NT*NG + g*NH + jb0 + jh*16];

  uint2 hpk[2]; hpk[0].x=0u; hpk[0].y=0u; hpk[1].x=0u; hpk[1].y=0u;
  __syncthreads();

  for (int t = 0; t < NT; ++t) {
    const int cur = t & 1, nxt = cur ^ 1;
    const int tn = (t+1 < NT) ? t+1 : t;
    #pragma unroll
    for (int jh = 0; jh < 2; ++jh) {
      f32x4 ar = {0.f,0.f,0.f,0.f}, az = ar, an = ar;
      #pragma unroll
      for (int kb = 0; kb < 8; ++kb) {
        short8 bfr = *(const short8*)&hfrag[cur][kb][l*8];
        ar = __builtin_amdgcn_mfma_f32_16x16x32_bf16(wf[0][jh][kb], bfr, ar, 0,0,0);
        az = __builtin_amdgcn_mfma_f32_16x16x32_bf16(wf[1][jh][kb], bfr, az, 0,0,0);
        an = __builtin_amdgcn_mfma_f32_16x16x32_bf16(wf[2][jh][kb], bfr, an, 0,0,0);
      }
      uint2 xr2 = xp[0][jh], xz2 = xp[1][jh], xn2 = xp[2][jh], hp2 = hpk[jh];
      // prefetch next step's xproj for this jh (hidden under next step's MFMA+gates)
      const u16* xnx = &xproj[((size_t)bb*NT + tn)*NG + jb0 + jh*16];
      xp[0][jh] = *(const uint2*)(xnx);
      xp[1][jh] = *(const uint2*)(xnx + NH);
      xp[2][jh] = *(const uint2*)(xnx + 2*NH);
      u32 dlo = 0u, dhi = 0u;
      #pragma unroll
      for (int r = 0; r < 4; ++r) {
        u32 xrw = (r < 2) ? xr2.x : xr2.y;
        u32 xzw = (r < 2) ? xz2.x : xz2.y;
        u32 xnw = (r < 2) ? xn2.x : xn2.y;
        u32 hpw = (r < 2) ? hp2.x : hp2.y;
        float xr = (r & 1) ? hi_bf(xrw) : lo_bf(xrw);
        float xz = (r & 1) ? hi_bf(xzw) : lo_bf(xzw);
        float xn = (r & 1) ? hi_bf(xnw) : lo_bf(xnw);
        float hp = (r & 1) ? hi_bf(hpw) : lo_bf(hpw);
        float rr = sigf(xr + ar[r]);
        float zz = sigf(xz + az[r]);
        float nn = tanhf_(xn + rr*(an[r] + bhn[jh][r]));
        float hnew = (1.f - zz)*nn + zz*hp;
        u16 hb = f2bf(hnew);
        if (r == 0)      dlo  = hb;
        else if (r == 1) dlo |= ((u32)hb << 16);
        else if (r == 2) dhi  = hb;
        else             dhi |= ((u32)hb << 16);
      }
      uint2 hw; hw.x = dlo; hw.y = dhi;
      hpk[jh] = hw;
      if (c < 8) {
        int lp = c + 16*(jh*2 + (q >> 1));         // B-frag lane for next step
        *(uint2*)&hfrag[nxt][w][lp*8 + (q & 1)*4] = hw;
        if (write_all)
          *(uint2*)&outp[((size_t)(b0+c)*NT + t)*NH + jb0 + jh*16] = hw;
        else if (t == NT-1)
          *(uint2*)&outp[(size_t)(b0+c)*NH + jb0 + jh*16] = hw;
      }
    }
    __syncthreads();
  }
}

// ---------------------------------------------------------------------------
__global__ __launch_bounds__(256) void fc_kernel(const u16* __restrict__ hT,
    const float* __restrict__ Wfc, const float* __restrict__ bfc, float* __restrict__ out)
{
  __shared__ float wv[NH];
  int tid = threadIdx.x;
  if (tid < NH) wv[tid] = Wfc[tid];
  __syncthreads();
  if (tid < NB) {
    float acc = bfc[0];
    for (int j = 0; j < NH; ++j) acc += lo_bf((u32)hT[tid*NH + j]) * wv[j];
    out[tid] = sigf(acc);
  }
}

// ---------------------------------------------------------------------------
extern "C" void kernel_launch(void* const* d_in, const int* in_sizes, int n_in,
                              void* d_out, int out_size, void* d_ws, size_t ws_size,
                              hipStream_t stream) {
  const float* x    = (const float*)d_in[0];
  const float* Wih0 = (const float*)d_in[1];
  const float* Whh0 = (const float*)d_in[2];
  const float* bih0 = (const float*)d_in[3];
  const float* bhh0 = (const float*)d_in[4];
  const float* Wih1 = (const float*)d_in[5];
  const float* Whh1 = (const float*)d_in[6];
  const float* bih1 = (const float*)d_in[7];
  const float* bhh1 = (const float*)d_in[8];
  const float* Wfc  = (const float*)d_in[9];
  const float* bfc  = (const float*)d_in[10];

  char* ws = (char*)d_ws;
  u16*   xproj = (u16*)ws;                                   // 100,663,296 B
  u16*   xbf   = (u16*)(ws + 100663296);                     // 33,554,432 B
  u16*   out0  = xbf;                                        // aliases xbf (xbf dead after GEMM0)
  u16*   w0bf  = (u16*)(ws + 134217728);                     // 393,216 B
  u16*   w1bf  = (u16*)(ws + 134610944);                     // 393,216 B
  float* bias0 = (float*)(ws + 135004160);                   // 3,072 B
  float* bias1 = (float*)(ws + 135007232);                   // 3,072 B
  u16*   hT    = (u16*)(ws + 135010304);                     // 65,536 B

  convert_kernel<<<dim3(2048), dim3(256), 0, stream>>>(
      x, Wih0, Wih1, bih0, bhh0, bih1, bhh1, xbf, w0bf, w1bf, bias0, bias1);
  gemm_proj<<<dim3(1024*24), dim3(256), 0, stream>>>(xbf, w0bf, bias0, xproj);
  recur_kernel<<<dim3(16), dim3(512), 0, stream>>>(xproj, Whh0, bhh0, out0, 1);
  gemm_proj<<<dim3(1024*24), dim3(256), 0, stream>>>(out0, w1bf, bias1, xproj);
  recur_kernel<<<dim3(16), dim3(512), 0, stream>>>(xproj, Whh1, bhh1, hT, 0);
  fc_kernel<<<dim3(1), dim3(256), 0, stream>>>(hT, Wfc, bfc, (float*)d_out);
}

// Round 3
// 1399.448 us; speedup vs baseline: 8.9296x; 1.8078x over previous
//
#include <hip/hip_runtime.h>
#include <hip/hip_bf16.h>
#include <stdint.h>

#define NB 128
#define NT 512
#define NI 256
#define NH 256
#define NG 768          // 3*NH

typedef unsigned int u32;
typedef unsigned short u16;
typedef __attribute__((ext_vector_type(8))) short short8;
typedef __attribute__((ext_vector_type(4))) float f32x4;

__device__ __forceinline__ float lo_bf(u32 u){ return __uint_as_float(u << 16); }
__device__ __forceinline__ float hi_bf(u32 u){ return __uint_as_float(u & 0xffff0000u); }
__device__ __forceinline__ u16 f2bf(float f){
  u32 u = __float_as_uint(f);
  u += 0x7fffu + ((u >> 16) & 1u);   // RNE
  return (u16)(u >> 16);
}
__device__ __forceinline__ u32 pack2(float a, float b){
  return (u32)f2bf(a) | ((u32)f2bf(b) << 16);
}
__device__ __forceinline__ u32 pack_rne(float a, float b){
  u32 ua = __float_as_uint(a), ub = __float_as_uint(b);
  ua += 0x7fffu + ((ua >> 16) & 1u);
  ub += 0x7fffu + ((ub >> 16) & 1u);
  return (ua >> 16) | (ub & 0xffff0000u);
}
__device__ __forceinline__ float sigf(float v){
  return __builtin_amdgcn_rcpf(1.f + __expf(-v));
}
__device__ __forceinline__ float tanhf_(float u){
  float e = __expf(2.f*u);
  return 1.f - 2.f*__builtin_amdgcn_rcpf(e + 1.f);
}
__device__ __forceinline__ void gload_lds16(const void* g, void* l){
  __builtin_amdgcn_global_load_lds((const __attribute__((address_space(1))) void*)g,
                                   (__attribute__((address_space(3))) void*)l, 16, 0, 0);
}

// ---------------------------------------------------------------------------
// fp32 -> bf16 conversions + combined bias vectors
// ---------------------------------------------------------------------------
__global__ void convert_kernel(const float* __restrict__ x,
    const float* __restrict__ Wih0, const float* __restrict__ Wih1,
    const float* __restrict__ bih0, const float* __restrict__ bhh0,
    const float* __restrict__ bih1, const float* __restrict__ bhh1,
    u16* __restrict__ xbf, u16* __restrict__ w0bf, u16* __restrict__ w1bf,
    float* __restrict__ bias0, float* __restrict__ bias1)
{
  const int NX4 = NB*NT*NI/4, NW4 = NG*NH/4;
  int gid = blockIdx.x*blockDim.x + threadIdx.x;
  for (int i = gid; i < NX4 + 2*NW4; i += gridDim.x*blockDim.x) {
    const float* s; u16* d; int o;
    if (i < NX4)          { s = x;    d = xbf;  o = i; }
    else if (i < NX4+NW4) { s = Wih0; d = w0bf; o = i - NX4; }
    else                  { s = Wih1; d = w1bf; o = i - NX4 - NW4; }
    float4 v = *(const float4*)(s + (size_t)o*4);
    uint2 pk; pk.x = pack2(v.x, v.y); pk.y = pack2(v.z, v.w);
    *(uint2*)&d[(size_t)o*4] = pk;
  }
  // bias_comb[g] = bih[g] + (g in r,z ? bhh[g] : 0)   (bhh_n stays inside r*(...))
  if (gid < NG)            bias0[gid] = bih0[gid] + (gid < 2*NH ? bhh0[gid] : 0.f);
  else if (gid < 2*NG)   { int g = gid - NG; bias1[g] = bih1[g] + (g < 2*NH ? bhh1[g] : 0.f); }
}

// ---------------------------------------------------------------------------
// xproj[m][g] = sum_k A[m][k] * W[g][k] + bias[g]    (A:[M][256], W:[768][256])
// ---------------------------------------------------------------------------
__global__ __launch_bounds__(256, 2) void gemm_proj(const u16* __restrict__ A,
    const u16* __restrict__ W, const float* __restrict__ bias, u16* __restrict__ out)
{
  const int mt = blockIdx.x / 24, nt = blockIdx.x % 24;
  __shared__ __align__(16) u16 As[64*256];   // 32 KB
  __shared__ __align__(16) u16 Bs[32*256];   // 16 KB
  const int tid = threadIdx.x;
  const u16* Ag = A + (size_t)mt*64*256;
  const u16* Wg = W + (size_t)nt*32*256;
  #pragma unroll
  for (int i = 0; i < 8; ++i) {
    int ca = tid + 256*i, row = ca >> 5, sl = ca & 31;
    gload_lds16(Ag + row*256 + ((sl ^ (row&7))<<3), &As[ca<<3]);
  }
  #pragma unroll
  for (int i = 0; i < 4; ++i) {
    int cb = tid + 256*i, row = cb >> 5, sl = cb & 31;
    gload_lds16(Wg + row*256 + ((sl ^ (row&7))<<3), &Bs[cb<<3]);
  }
  __syncthreads();
  const int w = tid >> 6, l = tid & 63, c = l & 15, q = l >> 4;
  f32x4 acc0 = {0.f,0.f,0.f,0.f}, acc1 = acc0;
  const int arow = w*16 + c;
  #pragma unroll
  for (int kb = 0; kb < 8; ++kb) {
    int ks = kb*4 + q;
    short8 af  = *(const short8*)&As[arow*256 + ((ks ^ (arow&7))<<3)];
    short8 bf0 = *(const short8*)&Bs[c*256        + ((ks ^ (c&7))<<3)];
    short8 bf1 = *(const short8*)&Bs[(16+c)*256   + ((ks ^ ((16+c)&7))<<3)];
    acc0 = __builtin_amdgcn_mfma_f32_16x16x32_bf16(af, bf0, acc0, 0,0,0);
    acc1 = __builtin_amdgcn_mfma_f32_16x16x32_bf16(af, bf1, acc1, 0,0,0);
  }
  #pragma unroll
  for (int nf = 0; nf < 2; ++nf) {
    int g = nt*32 + nf*16 + c;
    float bs = bias[g];
    f32x4 av = nf ? acc1 : acc0;
    #pragma unroll
    for (int r = 0; r < 4; ++r) {
      int m = mt*64 + w*16 + q*4 + r;
      out[(size_t)m*NG + g] = f2bf(av[r] + bs);
    }
  }
}

// ---------------------------------------------------------------------------
// GRU recurrence. 16 wgs x 512 thr (8 waves). Wave w owns j in [32w,32w+32),
// all 3 gates, Whh resident in (A)GPRs. Gate math deduped by jh-half:
// lanes c<8 extract the jh=0 output tile, lanes c>=8 the jh=1 tile (true
// duplicates since B-frag cols 8..15 carry a copy of cols 0..7).
// ---------------------------------------------------------------------------
__global__ __launch_bounds__(512, 1) void recur_kernel(
    const u16* __restrict__ xproj,   // [NB*NT][768] bf16, biases folded (r,z incl bhh)
    const float* __restrict__ Whh,   // [768][256] fp32
    const float* __restrict__ bhh,   // [768] fp32 (n part used)
    u16* __restrict__ outp,          // write_all: [NB][NT][256] ; else hT [NB][256]
    int write_all)
{
  const int b0 = blockIdx.x * 8;
  const int tid = threadIdx.x;
  const int w = tid >> 6, l = tid & 63, c = l & 15, q = l >> 4;
  const int jh = c >> 3;                 // this lane's extraction half
  const bool lo8 = (jh == 0);
  const int bb = b0 + (c & 7);           // this lane's batch
  const int jb = 32*w + jh*16 + q*4;     // this lane's 4-j base

  __shared__ __align__(16) u16 hfrag[2][8][512];   // 16 KB
  for (int i = tid; i < 4096; i += 512) ((u32*)hfrag)[i] = 0u;

  // ---- resident weight fragments wf[gate][jh][kb] (48 frags) ----
  short8 wf[3][2][8];
  #pragma unroll
  for (int g = 0; g < 3; ++g)
    #pragma unroll
    for (int jj = 0; jj < 2; ++jj) {
      const float* src = Whh + ((size_t)(g*NH + 32*w + jj*16 + c))*NI + q*8;
      #pragma unroll
      for (int kb = 0; kb < 8; ++kb) {
        float4 f0 = *(const float4*)(src + kb*32);
        float4 f1 = *(const float4*)(src + kb*32 + 4);
        short8 s;
        s[0]=(short)f2bf(f0.x); s[1]=(short)f2bf(f0.y);
        s[2]=(short)f2bf(f0.z); s[3]=(short)f2bf(f0.w);
        s[4]=(short)f2bf(f1.x); s[5]=(short)f2bf(f1.y);
        s[6]=(short)f2bf(f1.z); s[7]=(short)f2bf(f1.w);
        wf[g][jj][kb] = s;
      }
    }

  // n-gate hidden-bias as accumulator init vectors (j = 32w + q*4 + r  [+16])
  float4 bt0 = *(const float4*)&bhh[2*NH + 32*w + q*4];
  float4 bt1 = *(const float4*)&bhh[2*NH + 32*w + q*4 + 16];
  f32x4 bhn0; bhn0[0]=bt0.x; bhn0[1]=bt0.y; bhn0[2]=bt0.z; bhn0[3]=bt0.w;
  f32x4 bhn1; bhn1[0]=bt1.x; bhn1[1]=bt1.y; bhn1[2]=bt1.z; bhn1[3]=bt1.w;

  const u16* xptr = xproj + (size_t)bb*NT*NG + jb;
  uint2 xpr = *(const uint2*)(xptr);            // r-gate, 4 bf16
  uint2 xpz = *(const uint2*)(xptr + NH);
  uint2 xpn = *(const uint2*)(xptr + 2*NH);
  uint2 hpk; hpk.x = 0u; hpk.y = 0u;            // own 4 h_prev (bf16)

  const int lp = (c & 7) + 16*(2*jh + (q >> 1));
  __syncthreads();

  #pragma unroll 1
  for (int t = 0; t < NT; ++t) {
    const int cur = t & 1, nxt = cur ^ 1;

    // ---- hoisted B-fragment reads (8 x ds_read_b128, reused by all chains) --
    short8 bfr[8];
    #pragma unroll
    for (int kb = 0; kb < 8; ++kb) bfr[kb] = *(const short8*)&hfrag[cur][kb][l*8];

    // ---- prefetch next step's xproj ----
    const u16* xnx = xptr + (size_t)((t+1 < NT) ? t+1 : t)*NG;
    uint2 nxr = *(const uint2*)(xnx);
    uint2 nxz = *(const uint2*)(xnx + NH);
    uint2 nxn = *(const uint2*)(xnx + 2*NH);

    // ---- 6 independent 8-deep MFMA chains ----
    f32x4 z4 = {0.f,0.f,0.f,0.f};
    f32x4 ar0 = z4, az0 = z4, ar1 = z4, az1 = z4;
    f32x4 an0 = bhn0, an1 = bhn1;
    #pragma unroll
    for (int kb = 0; kb < 8; ++kb) {
      short8 bv = bfr[kb];
      ar0 = __builtin_amdgcn_mfma_f32_16x16x32_bf16(wf[0][0][kb], bv, ar0, 0,0,0);
      az0 = __builtin_amdgcn_mfma_f32_16x16x32_bf16(wf[1][0][kb], bv, az0, 0,0,0);
      an0 = __builtin_amdgcn_mfma_f32_16x16x32_bf16(wf[2][0][kb], bv, an0, 0,0,0);
      ar1 = __builtin_amdgcn_mfma_f32_16x16x32_bf16(wf[0][1][kb], bv, ar1, 0,0,0);
      az1 = __builtin_amdgcn_mfma_f32_16x16x32_bf16(wf[1][1][kb], bv, az1, 0,0,0);
      an1 = __builtin_amdgcn_mfma_f32_16x16x32_bf16(wf[2][1][kb], bv, an1, 0,0,0);
    }

    // ---- gate math: 4 h-values per lane (this lane's jh tile) ----
    float hv[4];
    #pragma unroll
    for (int r = 0; r < 4; ++r) {
      float arv = lo8 ? ar0[r] : ar1[r];
      float azv = lo8 ? az0[r] : az1[r];
      float anv = lo8 ? an0[r] : an1[r];     // includes bhh_n via init
      u32 xrw = (r < 2) ? xpr.x : xpr.y;
      u32 xzw = (r < 2) ? xpz.x : xpz.y;
      u32 xnw = (r < 2) ? xpn.x : xpn.y;
      u32 hpw = (r < 2) ? hpk.x : hpk.y;
      float xr = (r & 1) ? hi_bf(xrw) : lo_bf(xrw);
      float xz = (r & 1) ? hi_bf(xzw) : lo_bf(xzw);
      float xn = (r & 1) ? hi_bf(xnw) : lo_bf(xnw);
      float hp = (r & 1) ? hi_bf(hpw) : lo_bf(hpw);
      float rr = sigf(xr + arv);
      float zz = sigf(xz + azv);
      float nn = tanhf_(__builtin_fmaf(rr, anv, xn));
      hv[r] = __builtin_fmaf(zz, hp - nn, nn);   // (1-z)n + z h
    }
    hpk.x = pack_rne(hv[0], hv[1]);
    hpk.y = pack_rne(hv[2], hv[3]);

    // ---- write h into next B-frag (both column copies) + output ----
    u16* hdst = &hfrag[nxt][w][lp*8 + (q & 1)*4];
    *(uint2*)hdst        = hpk;   // cols 0..7
    *(uint2*)(hdst + 64) = hpk;   // duplicate cols 8..15
    if (write_all)
      *(uint2*)&outp[((size_t)bb*NT + t)*NH + jb] = hpk;
    else if (t == NT-1)
      *(uint2*)&outp[(size_t)bb*NH + jb] = hpk;

    xpr = nxr; xpz = nxz; xpn = nxn;
    __syncthreads();
  }
}

// ---------------------------------------------------------------------------
__global__ __launch_bounds__(256) void fc_kernel(const u16* __restrict__ hT,
    const float* __restrict__ Wfc, const float* __restrict__ bfc, float* __restrict__ out)
{
  __shared__ float wv[NH];
  int tid = threadIdx.x;
  if (tid < NH) wv[tid] = Wfc[tid];
  __syncthreads();
  if (tid < NB) {
    float acc = bfc[0];
    for (int j = 0; j < NH; ++j) acc += lo_bf((u32)hT[tid*NH + j]) * wv[j];
    out[tid] = sigf(acc);
  }
}

// ---------------------------------------------------------------------------
extern "C" void kernel_launch(void* const* d_in, const int* in_sizes, int n_in,
                              void* d_out, int out_size, void* d_ws, size_t ws_size,
                              hipStream_t stream) {
  const float* x    = (const float*)d_in[0];
  const float* Wih0 = (const float*)d_in[1];
  const float* Whh0 = (const float*)d_in[2];
  const float* bih0 = (const float*)d_in[3];
  const float* bhh0 = (const float*)d_in[4];
  const float* Wih1 = (const float*)d_in[5];
  const float* Whh1 = (const float*)d_in[6];
  const float* bih1 = (const float*)d_in[7];
  const float* bhh1 = (const float*)d_in[8];
  const float* Wfc  = (const float*)d_in[9];
  const float* bfc  = (const float*)d_in[10];

  char* ws = (char*)d_ws;
  u16*   xproj = (u16*)ws;                                   // 100,663,296 B
  u16*   xbf   = (u16*)(ws + 100663296);                     // 33,554,432 B
  u16*   out0  = xbf;                                        // aliases xbf (dead after GEMM0)
  u16*   w0bf  = (u16*)(ws + 134217728);
  u16*   w1bf  = (u16*)(ws + 134610944);
  float* bias0 = (float*)(ws + 135004160);
  float* bias1 = (float*)(ws + 135007232);
  u16*   hT    = (u16*)(ws + 135010304);

  convert_kernel<<<dim3(2048), dim3(256), 0, stream>>>(
      x, Wih0, Wih1, bih0, bhh0, bih1, bhh1, xbf, w0bf, w1bf, bias0, bias1);
  gemm_proj<<<dim3(1024*24), dim3(256), 0, stream>>>(xbf, w0bf, bias0, xproj);
  recur_kernel<<<dim3(16), dim3(512), 0, stream>>>(xproj, Whh0, bhh0, out0, 1);
  gemm_proj<<<dim3(1024*24), dim3(256), 0, stream>>>(out0, w1bf, bias1, xproj);
  recur_kernel<<<dim3(16), dim3(512), 0, stream>>>(xproj, Whh1, bhh1, hT, 0);
  fc_kernel<<<dim3(1), dim3(256), 0, stream>>>(hT, Wfc, bfc, (float*)d_out);
}